// Round 2
// baseline (604.685 us; speedup 1.0000x reference)
//
#include <hip/hip_runtime.h>

#define D_DIM 128
#define NEG_SLOPE 0.2f

// Each 32-lane group processes 4 consecutive rows per iteration:
//  - 8 independent float4 loads in flight (4 from Wx_i, 4 from Wx_j) -> MLP
//  - one 5-step shuffle chain reduces all 4 rows together
//  - lane 0 writes the 4 results as a single coalesced float4
// Persistent grid (2048 blocks = 8/CU), grid-stride over row-chunks.
__global__ __launch_bounds__(256) void gat_score_kernel(
    const float* __restrict__ Wx_i,
    const float* __restrict__ Wx_j,
    const float* __restrict__ a,
    float* __restrict__ out,
    int E)
{
    const int tid  = threadIdx.x;
    const int lane = tid & 31;                       // slot within a row (0..31)
    const int group = (blockIdx.x << 3) | (tid >> 5); // global 32-lane group id
    const int numGroups = gridDim.x << 3;

    // Per-lane slice of the attention vector (1KB total, lives in registers)
    const float4 as = ((const float4*)a)[lane];            // a_src
    const float4 ad = ((const float4*)(a + D_DIM))[lane];  // a_dst

    // E is a multiple of 4; each chunk is 4 full rows.
    for (int row0 = group * 4; row0 < E; row0 += numGroups * 4) {
        const float4* pi = (const float4*)(Wx_i + (size_t)row0 * D_DIM) + lane;
        const float4* pj = (const float4*)(Wx_j + (size_t)row0 * D_DIM) + lane;

        // 8 independent loads, issued back-to-back (row stride = 32 float4)
        const float4 xi0 = pi[0],  xi1 = pi[32], xi2 = pi[64], xi3 = pi[96];
        const float4 xj0 = pj[0],  xj1 = pj[32], xj2 = pj[64], xj3 = pj[96];

        float s0 = xi0.x*as.x + xi0.y*as.y + xi0.z*as.z + xi0.w*as.w
                 + xj0.x*ad.x + xj0.y*ad.y + xj0.z*ad.z + xj0.w*ad.w;
        float s1 = xi1.x*as.x + xi1.y*as.y + xi1.z*as.z + xi1.w*as.w
                 + xj1.x*ad.x + xj1.y*ad.y + xj1.z*ad.z + xj1.w*ad.w;
        float s2 = xi2.x*as.x + xi2.y*as.y + xi2.z*as.z + xi2.w*as.w
                 + xj2.x*ad.x + xj2.y*ad.y + xj2.z*ad.z + xj2.w*ad.w;
        float s3 = xi3.x*as.x + xi3.y*as.y + xi3.z*as.z + xi3.w*as.w
                 + xj3.x*ad.x + xj3.y*ad.y + xj3.z*ad.z + xj3.w*ad.w;

        // One shared reduction chain for all 4 rows
        #pragma unroll
        for (int off = 16; off > 0; off >>= 1) {
            s0 += __shfl_down(s0, off, 32);
            s1 += __shfl_down(s1, off, 32);
            s2 += __shfl_down(s2, off, 32);
            s3 += __shfl_down(s3, off, 32);
        }

        if (lane == 0) {
            float4 r;
            r.x = (s0 > 0.0f) ? s0 : NEG_SLOPE * s0;
            r.y = (s1 > 0.0f) ? s1 : NEG_SLOPE * s1;
            r.z = (s2 > 0.0f) ? s2 : NEG_SLOPE * s2;
            r.w = (s3 > 0.0f) ? s3 : NEG_SLOPE * s3;
            ((float4*)out)[row0 >> 2] = r;  // 4 consecutive rows, 16B aligned
        }
    }
}

extern "C" void kernel_launch(void* const* d_in, const int* in_sizes, int n_in,
                              void* d_out, int out_size, void* d_ws, size_t ws_size,
                              hipStream_t stream) {
    const float* Wx_i = (const float*)d_in[0];
    const float* Wx_j = (const float*)d_in[1];
    const float* a    = (const float*)d_in[2];
    float* out = (float*)d_out;

    const int E = out_size;   // 640000
    // Persistent-ish grid: 8 blocks/CU * 256 CUs
    const int grid = 2048;

    gat_score_kernel<<<grid, 256, 0, stream>>>(Wx_i, Wx_j, a, out, E);
}